// Round 7
// baseline (494.613 us; speedup 1.0000x reference)
//
#include <hip/hip_runtime.h>
#include <hip/hip_cooperative_groups.h>

namespace cg = cooperative_groups;

// ConvLSTM2D: B=16,T=8,H=W=256,C=3,F=64,stride=16 -> Ho=Wo=16, 4F=256
#define NB   16
#define NT   8
#define HIN  256
#define CIN  3
#define NF   64
#define OC   256
#define HO   16
#define WOUT 16

typedef short short8 __attribute__((ext_vector_type(8)));
typedef float f32x16 __attribute__((ext_vector_type(16)));

__device__ __forceinline__ unsigned short f2bf(float x) {
  union { float f; unsigned int u; } v; v.f = x;
  unsigned int r = v.u + 0x7fffu + ((v.u >> 16) & 1u);
  return (unsigned short)(r >> 16);
}

// ---------------- Kernel 1: strided input conv, permuted-column output -------
// n = (oc&63)*4 + (oc>>6)  (filter-major, gate-minor); bias folded in.
__global__ __launch_bounds__(256) void input_conv(
    const float* __restrict__ x, const float* __restrict__ Wx,
    const float* __restrict__ bias, float* __restrict__ xc)
{
  const int ho = blockIdx.x;
  const int bt = blockIdx.y;
  const int oc = threadIdx.x;

  __shared__ float patch[3 * 16 * 12];  // k padded 9->12 for float4 reads
  for (int idx = threadIdx.x; idx < 432; idx += 256) {
    int r = idx / 144, rem = idx % 144;
    int wo = rem / 9, k = rem % 9;
    int kw = k / 3, c = k % 3;
    patch[(r * 16 + wo) * 12 + k] =
        x[(((size_t)bt * HIN + (ho * 16 + r)) * HIN + (wo * 16 + kw)) * CIN + c];
  }
  float w[27];
#pragma unroll
  for (int k = 0; k < 27; ++k) w[k] = Wx[(size_t)k * OC + oc];
  __syncthreads();

  const float bv = bias[oc];
  const int n = (oc & 63) * 4 + (oc >> 6);
  for (int wo = 0; wo < 16; ++wo) {
    float acc = bv;
#pragma unroll
    for (int kh = 0; kh < 3; ++kh) {
      const float* pp = &patch[(kh * 16 + wo) * 12];
      float4 p0 = *(const float4*)pp;
      float4 p1 = *(const float4*)(pp + 4);
      float p8 = pp[8];
      const float* wk = &w[kh * 9];
      acc = fmaf(p0.x, wk[0], fmaf(p0.y, wk[1], fmaf(p0.z, wk[2], acc)));
      acc = fmaf(p0.w, wk[3], fmaf(p1.x, wk[4], fmaf(p1.y, wk[5], acc)));
      acc = fmaf(p1.z, wk[6], fmaf(p1.w, wk[7], fmaf(p8, wk[8], acc)));
    }
    xc[(((size_t)bt * HO + ho) * WOUT + wo) * OC + n] = acc;
  }
}

// ---------------- Kernel 2: Wh -> bf16 fragment panels (coalesced transpose) -
// Bp[nb(8)][u(36: tap*4+q)][lane(64)][j(8)] bf16; n = nb*32+(lane&31),
// ci = q*16+(lane>>5)*8+j. One block per tap; Wh tap-slice staged in LDS.
__global__ __launch_bounds__(256) void conv_weights(
    const float* __restrict__ Wh, unsigned short* __restrict__ Bp)
{
  __shared__ float wt[64 * 256];  // [ci][oc], 64 KB
  const int tap = blockIdx.x;
  const int t = threadIdx.x;
#pragma unroll
  for (int i = 0; i < 16; ++i) {
    int chunk = t + i * 256;  // 4096 float4 chunks
    *(float4*)&wt[chunk * 4] = *(const float4*)&Wh[(size_t)tap * 16384 + chunk * 4];
  }
  __syncthreads();
#pragma unroll
  for (int rep = 0; rep < 8; ++rep) {
    int u = t + rep * 256;          // (nb,q,l) flat, 2048 total
    int nb = u >> 8, q = (u >> 6) & 3, l = u & 63;
    int n = nb * 32 + (l & 31);
    int oc = (n & 3) * 64 + (n >> 2);   // inverse column permutation
    int ci0 = q * 16 + (l >> 5) * 8;
    short8 v;
#pragma unroll
    for (int j = 0; j < 8; ++j) v[j] = (short)f2bf(wt[(ci0 + j) * 256 + oc]);
    *(short8*)&Bp[(size_t)((nb * 36 + tap * 4 + q) * 64 + l) * 8] = v;
  }
}

// ---------------- Shared per-step body (used by both launch modes) ----------
#define A_BYTES 23040   // 180 cells * 128 B
#define B_BYTES 36864   // 36 units * 1024 B

// ---------------- Kernel 3a: cooperative fused recurrence --------------------
// All 8 LSTM steps in one launch; grid.sync() between steps. Per-block tile as
// R5: block = (bid>>3 -> mb 0..31, bid&7 -> nb), m-tile 128, n-tile 32,
// 8 waves = 4 mf x 2 kk. B panel staged in LDS ONCE; A halo restaged per step;
// z overlays the A region only ([2][32][68] f32, two m-half epilogue passes).
__global__ __launch_bounds__(512, 2) void lstm_all(
    const float* __restrict__ xc, const unsigned short* __restrict__ Bp,
    unsigned short* __restrict__ h0, unsigned short* __restrict__ h1,
    float* __restrict__ c_st, float* __restrict__ out)
{
  cg::grid_group grid = cg::this_grid();

  const int bid = blockIdx.x;
  const int mb  = bid >> 3;          // 0..31
  const int nb  = bid & 7;           // 0..7
  const int b   = mb >> 1;
  const int ho0 = (mb & 1) * 8;
  const int tid = threadIdx.x;
  const int w    = tid >> 6;
  const int lane = tid & 63;
  const int mf = w >> 1, kk = w & 1;

  __shared__ __align__(16) char smem[A_BYTES + B_BYTES];   // 59,904 B
  unsigned short* Bs = (unsigned short*)(smem + A_BYTES);
  float* zs = (float*)smem;          // overlay on A region: [2][32][68] f32

  // ---- stage B once (persistent for all steps) ----
  for (int j = tid; j < 2304; j += 512)
    *(float4*)((char*)Bs + j * 16) = *(const float4*)(Bp + (size_t)nb * 18432 + j * 8);
  __syncthreads();

  // per-lane A center cell: local pos p -> (row+1, col+1) in 10x18 pad grid
  const int p = mf * 32 + (lane & 31);
  const int cell0 = ((p >> 4) + 1) * 18 + (p & 15) + 1;
  const int cib = (lane >> 5) * 16;   // byte half-offset within 32B k-quarter

  for (int t = 0; t < NT; ++t) {
    const int first = (t == 0), last = (t == NT - 1);
    const unsigned short* h_in  = (t & 1) ? h1 : h0;
    unsigned short*       h_out = (t & 1) ? h0 : h1;

    f32x16 acc = (f32x16)(0.0f);

    if (!first) {
      grid.sync();   // h_in fully written by all blocks of previous step

      // ---- stage A: 1440 16B chunks (10x18 halo cells x 128 B, zero-padded)
      for (int j = tid; j < 1440; j += 512) {
        int cell = j >> 3, sub = j & 7;
        int r = cell / 18, c = cell - r * 18;
        int y = ho0 + r - 1, xcol = c - 1;
        float4 v = make_float4(0.f, 0.f, 0.f, 0.f);
        if ((unsigned)y < 16u && (unsigned)xcol < 16u)
          v = *(const float4*)(h_in + (((size_t)b * 256 + y * 16 + xcol) * 64 + sub * 8));
        int byte = (cell * 128 + sub * 16) ^ ((cell & 7) << 4);  // T2 swizzle
        *(float4*)(smem + byte) = v;
      }
      __syncthreads();

#pragma unroll
      for (int uu = 0; uu < 18; ++uu) {
        const int u = uu * 2 + kk;       // this wave's k-units
        const int tap = u >> 2, q = u & 3;
        const int dy = tap / 3 - 1, dx = tap % 3 - 1;
        const int cell = cell0 + dy * 18 + dx;
        const int abyte = (cell * 128 + q * 32 + cib) ^ ((cell & 7) << 4);
        short8 a  = *(const short8*)(smem + abyte);
        short8 bb = *(const short8*)((const char*)Bs + u * 1024 + lane * 16);
        acc = __builtin_amdgcn_mfma_f32_32x32x16_bf16(a, bb, acc, 0, 0, 0);
      }
      __syncthreads();  // A dead; safe to overlay z
    }

    // ---- epilogue in two m-halves (z fits in A region, B stays live) ----
    const int col = lane & 31;
#pragma unroll
    for (int hp = 0; hp < 2; ++hp) {
      if (!first && (mf >> 1) == hp) {
        // dump partials: zs[(kk*32+col)*68 + (mf&1)*32 + row]
#pragma unroll
        for (int rr = 0; rr < 4; ++rr) {
          int off = (mf & 1) * 32 + rr * 8 + (lane >> 5) * 4;
          float4 vv = make_float4(acc[rr * 4], acc[rr * 4 + 1],
                                  acc[rr * 4 + 2], acc[rr * 4 + 3]);
          *(float4*)&zs[(kk * 32 + col) * 68 + off] = vv;
        }
      }
      __syncthreads();

      // 512 threads, one (pos,f) cell each: pos_l = tid&63, fl = tid>>6
      const int pos_l = tid & 63;
      const int fl    = tid >> 6;       // 0..7 local filter
      float z0 = 0.f, z1 = 0.f, z2 = 0.f, z3 = 0.f;
      if (!first) {
        z0 = zs[(fl * 4 + 0) * 68 + pos_l] + zs[(32 + fl * 4 + 0) * 68 + pos_l];
        z1 = zs[(fl * 4 + 1) * 68 + pos_l] + zs[(32 + fl * 4 + 1) * 68 + pos_l];
        z2 = zs[(fl * 4 + 2) * 68 + pos_l] + zs[(32 + fl * 4 + 2) * 68 + pos_l];
        z3 = zs[(fl * 4 + 3) * 68 + pos_l] + zs[(32 + fl * 4 + 3) * 68 + pos_l];
      }
      const int gpos = ho0 * 16 + hp * 64 + pos_l;
      const float4 xq = *(const float4*)&xc[(((size_t)(b * NT + t) * 256 + gpos)) * 256 + nb * 32 + fl * 4];
      float zi = z0 + xq.x, zf_ = z1 + xq.y, zg = z2 + xq.z, zo = z3 + xq.w;
      float ig = fminf(fmaxf(fmaf(zi, 0.2f, 0.5f), 0.f), 1.f);
      float fg = fminf(fmaxf(fmaf(zf_, 0.2f, 0.5f), 0.f), 1.f);
      float og = fminf(fmaxf(fmaf(zo, 0.2f, 0.5f), 0.f), 1.f);
      size_t ci = ((size_t)b * 256 + gpos) * 64 + nb * 8 + fl;
      float cold = first ? 0.f : c_st[ci];
      float cn = fmaf(fg, cold, ig * zg);
      c_st[ci] = cn;
      float h = og * cn;
      h_out[ci] = f2bf(h);
      if (last) out[ci] = h;
      __syncthreads();   // zs reads done before next half / next step overwrites
    }
  }
}

// ---------------- Kernel 3b: per-step fallback (R5-validated path) ----------
__global__ __launch_bounds__(512, 2) void lstm_step(
    const float* __restrict__ xc, const unsigned short* __restrict__ Bp,
    const unsigned short* __restrict__ h_in, unsigned short* __restrict__ h_out,
    float* __restrict__ c_st, float* __restrict__ out,
    int t, int first, int last)
{
  const int mb  = blockIdx.x;        // 0..31
  const int nb  = blockIdx.y;        // 0..7
  const int b   = mb >> 1;
  const int ho0 = (mb & 1) * 8;
  const int tid = threadIdx.x;
  const int w    = tid >> 6;
  const int lane = tid & 63;
  const int mf = w >> 1, kk = w & 1;

  __shared__ __align__(16) char smem[A_BYTES + B_BYTES];
  unsigned short* Bs = (unsigned short*)(smem + A_BYTES);
  float* zs = (float*)smem;          // overlay: z[2][32][129] f32

  f32x16 acc = (f32x16)(0.0f);

  if (!first) {
    for (int j = tid; j < 1440; j += 512) {
      int cell = j >> 3, sub = j & 7;
      int r = cell / 18, c = cell - r * 18;
      int y = ho0 + r - 1, xcol = c - 1;
      float4 v = make_float4(0.f, 0.f, 0.f, 0.f);
      if ((unsigned)y < 16u && (unsigned)xcol < 16u)
        v = *(const float4*)(h_in + (((size_t)b * 256 + y * 16 + xcol) * 64 + sub * 8));
      int byte = (cell * 128 + sub * 16) ^ ((cell & 7) << 4);
      *(float4*)(smem + byte) = v;
    }
    for (int j = tid; j < 2304; j += 512)
      *(float4*)((char*)Bs + j * 16) = *(const float4*)(Bp + (size_t)nb * 18432 + j * 8);
    __syncthreads();

    const int p = mf * 32 + (lane & 31);
    const int cell0 = ((p >> 4) + 1) * 18 + (p & 15) + 1;
    const int cib = (lane >> 5) * 16;

#pragma unroll
    for (int uu = 0; uu < 18; ++uu) {
      const int u = uu * 2 + kk;
      const int tap = u >> 2, q = u & 3;
      const int dy = tap / 3 - 1, dx = tap % 3 - 1;
      const int cell = cell0 + dy * 18 + dx;
      const int abyte = (cell * 128 + q * 32 + cib) ^ ((cell & 7) << 4);
      short8 a  = *(const short8*)(smem + abyte);
      short8 bb = *(const short8*)((const char*)Bs + u * 1024 + lane * 16);
      acc = __builtin_amdgcn_mfma_f32_32x32x16_bf16(a, bb, acc, 0, 0, 0);
    }
    __syncthreads();

    const int col = lane & 31;
#pragma unroll
    for (int rr = 0; rr < 4; ++rr) {
      int posl = mf * 32 + rr * 8 + (lane >> 5) * 4;
      float4 vv = make_float4(acc[rr * 4], acc[rr * 4 + 1], acc[rr * 4 + 2], acc[rr * 4 + 3]);
      *(float4*)&zs[(kk * 32 + col) * 129 + posl] = vv;
    }
  }
  __syncthreads();

  const int pos = tid & 127;
  const int fhalf = tid >> 7;
  const int gpos = ho0 * 16 + pos;
  const float* xcb = xc + ((size_t)(b * NT + t) * 256 + gpos) * 256 + nb * 32;
#pragma unroll
  for (int e = 0; e < 2; ++e) {
    int f = fhalf + e * 4;
    float zq0 = 0.f, zq1 = 0.f, zq2 = 0.f, zq3 = 0.f;
    if (!first) {
      zq0 = zs[(f * 4 + 0) * 129 + pos] + zs[(32 + f * 4 + 0) * 129 + pos];
      zq1 = zs[(f * 4 + 1) * 129 + pos] + zs[(32 + f * 4 + 1) * 129 + pos];
      zq2 = zs[(f * 4 + 2) * 129 + pos] + zs[(32 + f * 4 + 2) * 129 + pos];
      zq3 = zs[(f * 4 + 3) * 129 + pos] + zs[(32 + f * 4 + 3) * 129 + pos];
    }
    float4 xq = *(const float4*)(xcb + f * 4);
    float zi = zq0 + xq.x, zf_ = zq1 + xq.y, zg = zq2 + xq.z, zo = zq3 + xq.w;
    float ig = fminf(fmaxf(fmaf(zi, 0.2f, 0.5f), 0.f), 1.f);
    float fg = fminf(fmaxf(fmaf(zf_, 0.2f, 0.5f), 0.f), 1.f);
    float og = fminf(fmaxf(fmaf(zo, 0.2f, 0.5f), 0.f), 1.f);
    size_t ci = ((size_t)b * 256 + gpos) * 64 + nb * 8 + f;
    float cold = first ? 0.f : c_st[ci];
    float cn = fmaf(fg, cold, ig * zg);
    c_st[ci] = cn;
    float h = og * cn;
    h_out[ci] = f2bf(h);
    if (last) out[ci] = h;
  }
}

extern "C" void kernel_launch(void* const* d_in, const int* in_sizes, int n_in,
                              void* d_out, int out_size, void* d_ws, size_t ws_size,
                              hipStream_t stream) {
  const float* x    = (const float*)d_in[0];
  const float* Wx   = (const float*)d_in[1];
  const float* Wh   = (const float*)d_in[2];
  const float* bias = (const float*)d_in[3];
  float* out = (float*)d_out;

  char* ws = (char*)d_ws;
  float*          xc = (float*)ws;                         // 33,554,432 B
  unsigned short* Bp = (unsigned short*)(ws + 33554432);   //    294,912 B
  unsigned short* h0 = (unsigned short*)(ws + 33849344);   //    524,288 B
  unsigned short* h1 = (unsigned short*)(ws + 34373632);   //    524,288 B
  float*          cb = (float*)(ws + 34897920);            //  1,048,576 B

  input_conv<<<dim3(HO, NB * NT), 256, 0, stream>>>(x, Wx, bias, xc);
  conv_weights<<<9, 256, 0, stream>>>(Wh, Bp);

  void* args[] = { (void*)&xc, (void*)&Bp, (void*)&h0, (void*)&h1,
                   (void*)&cb, (void*)&out };
  hipError_t err = hipLaunchCooperativeKernel((const void*)lstm_all, dim3(256),
                                              dim3(512), args, 0, stream);
  if (err != hipSuccess) {
    // fallback: per-step launches (identical math)
    for (int t = 0; t < NT; ++t) {
      unsigned short* hin  = (t & 1) ? h1 : h0;
      unsigned short* hout = (t & 1) ? h0 : h1;
      lstm_step<<<dim3(32, 8), 512, 0, stream>>>(
          xc, Bp, hin, hout, cb, out, t, t == 0, t == NT - 1);
    }
  }
}